// Round 13
// baseline (630.875 us; speedup 1.0000x reference)
//
#include <hip/hip_runtime.h>

// ConvLSTM cell, MI355X. Implicit-GEMM over concat(x,h) channels, bf16 MFMA
// 32x32x16, fused in-register LSTM epilogue.
// R13: R12 with the buffer-flip bug fixed — baddr += (+/-24576) instead of
// XOR (24576 = 0x6000 overlaps plane-offset bits 13/14, so XOR != add).
// Rest unchanged: Wt relayout -> literal-offset A loads; precomputed B LDS
// addresses (0/1 VALU per read); A dist-2 (%3 slots); B dist-1 ping-pong;
// DMA at phase 1; counted vmcnt(4) barrier; last ibk peeled.

typedef __bf16 bf16x8 __attribute__((ext_vector_type(8)));
typedef float f32x16 __attribute__((ext_vector_type(16)));

#define PLANE_B  20736u                 // 324 positions * 64 B (18x18x32 bf16)
#define XH_BYTES (4096u * PLANE_B)      // 256 b * 16 icblk planes
#define OUT_HALF 16777216u              // B*CH*S

__device__ inline void gload_lds16(const void* g, void* l) {
    __builtin_amdgcn_global_load_lds(
        (const __attribute__((address_space(1))) void*)g,
        (__attribute__((address_space(3))) void*)l, 16, 0, 0);
}

// ---------------------------------------------------------------------------
// P1a: x,h (NCHW fp32) -> padded swizzled bf16 planes.
// addr = (p*64 + ofs) ^ ((p&7)<<4)  (bijective; same formula on read).
__global__ __launch_bounds__(256) void xh_transform(
    const float* __restrict__ x, const float* __restrict__ hh,
    unsigned char* __restrict__ xh)
{
    int blk = blockIdx.x;              // b*16 + ibk
    int b = blk >> 4, ibk = blk & 15;
    const float* src = (ibk < 8) ? (x  + ((size_t)(b*256 + ibk*32)) * 256)
                                 : (hh + ((size_t)(b*256 + (ibk-8)*32)) * 256);
    int t = threadIdx.x;               // t == spatial s
    uint32_t w[16];
#pragma unroll
    for (int i = 0; i < 16; ++i) {
        __bf16 lo = (__bf16)src[(size_t)(2*i  )*256 + t];
        __bf16 hi = (__bf16)src[(size_t)(2*i+1)*256 + t];
        w[i] = (uint32_t)__builtin_bit_cast(unsigned short, lo)
             | ((uint32_t)__builtin_bit_cast(unsigned short, hi) << 16);
    }
    unsigned char* plane = xh + (size_t)blk * PLANE_B;
    int p = ((t >> 4) + 1)*18 + (t & 15) + 1;      // interior position
    uint32_t key  = (uint32_t)(p & 7) << 4;
    uint32_t base = (uint32_t)p * 64u;
#pragma unroll
    for (int k = 0; k < 4; ++k)
        *(uint4*)(plane + ((base + 16u*k) ^ key)) =
            uint4{w[4*k], w[4*k+1], w[4*k+2], w[4*k+3]};
    // zero the 68 border positions (rows 0,17; cols 0,17)
    if (t < 68) {
        int pb;
        if      (t < 18) pb = t;                   // row 0
        else if (t < 36) pb = 17*18 + (t - 18);    // row 17
        else if (t < 52) pb = (t - 35)*18;         // rows 1..16, col 0
        else             pb = (t - 51)*18 + 17;    // rows 1..16, col 17
        uint32_t kb = (uint32_t)(pb & 7) << 4;
        uint32_t bb = (uint32_t)pb * 64u;
        uint4 z{0u,0u,0u,0u};
#pragma unroll
        for (int k = 0; k < 4; ++k)
            *(uint4*)(plane + ((bb + 16u*k) ^ kb)) = z;
    }
}

// ---------------------------------------------------------------------------
// P1b: Wx,Wh (OIHW fp32) -> Wt bf16 in A-fragment order.
// chunk = ((cbnh*16 + ibk)*9 + pos)*4 + half*2 + f ; 64 lanes x 8 bf16 each.
__global__ __launch_bounds__(256) void w_transform(
    const float* __restrict__ Wx, const float* __restrict__ Wh,
    __bf16* __restrict__ Wt)
{
    int idx  = blockIdx.x * 256 + threadIdx.x;   // 589824 total
    int lane = idx & 63;
    int chunk = idx >> 6;                        // 9216 chunks
    int f     = chunk & 1;
    int half  = (chunk >> 1) & 1;
    int pos   = (chunk >> 2) % 9;                // ky*3+kx
    int rest  = (chunk >> 2) / 9;                // 0..255
    int ibk   = rest & 15;
    int cbnh  = rest >> 4;
    int nh = cbnh & 1, cb = cbnh >> 1;
    int row = lane & 31, hl = lane >> 5;
    int gate = row & 3, ch8 = row >> 2;
    int oc  = gate*256 + cb*32 + (nh*2 + f)*8 + ch8;
    int ic0 = ibk*32 + half*16 + hl*8;
    bf16x8 v;
#pragma unroll
    for (int j = 0; j < 8; ++j) {
        int ic = ic0 + j;
        float w = (ic < 256) ? Wx[((size_t)oc*256 + ic      )*9 + pos]
                             : Wh[((size_t)oc*256 + (ic-256))*9 + pos];
        v[j] = (__bf16)w;
    }
    *(bf16x8*)(Wt + (size_t)chunk*512 + (size_t)lane*8) = v;
}

// ---------------------------------------------------------------------------
// Main. Block = (b, nh, cb): 256m x 64oc'. 4 waves, each 64m x 64oc:
// acc[2][2] f32x16 = 64 AGPR. 18 phases/ibk; A dist-2 (%3 slots), B dist-1
// ping-pong, DMA at phase 1, counted-vmcnt barrier. Last ibk peeled.
__global__ __launch_bounds__(256, 2) void convlstm_main(
    const unsigned char* __restrict__ xh, const __bf16* __restrict__ Wt,
    const float* __restrict__ bh,  const float* __restrict__ cin,
    const float* __restrict__ Wci, const float* __restrict__ Wcf,
    const float* __restrict__ Wco, float* __restrict__ out)
{
    int bid = blockIdx.x;               // b*16 + nh*8 + cb
    int cb  = bid & 7;
    int nh  = (bid >> 3) & 1;
    int b   = bid >> 4;
    int tid = threadIdx.x;
    int lane = tid & 63, wv = tid >> 6;
    int l31 = lane & 31, hl = lane >> 5;

    __shared__ __align__(16) unsigned char lds[2][24576];

    // accumulators init with bias bh[oc]
    f32x16 acc[2][2];
#pragma unroll
    for (int f = 0; f < 2; ++f) {
        int fg = nh*2 + f;
        f32x16 v;
#pragma unroll
        for (int r = 0; r < 16; ++r) {
            int gate = r & 3, q = r >> 2;
            v[r] = bh[gate*256 + cb*32 + fg*8 + 2*q + hl];
        }
        acc[0][f] = v; acc[1][f] = v;
    }

    const unsigned char* planes = xh + (size_t)b * (16u * PLANE_B);

    // stage plane 0 into buffer 0 (linear DMA; plane pre-padded+swizzled)
#pragma unroll
    for (int k = 0; k < 6; ++k)
        gload_lds16(planes + (size_t)(wv*6 + k)*1024u + (size_t)lane*16u,
                    &lds[0][(wv*6 + k)*1024 + lane*16]);

    // B LDS addresses: 9 pos x 2 m-frags, half=0, buffer 0.
    // byte(p,half) = (p*64 + hl*16 + half*32) ^ ((p&7)<<4)
    //              = baddr ^ (half*32)   [bit5 of pre-XOR base is 0]
    int m0 = wv*64 + l31, m1 = m0 + 32;
    int pb0 = (m0 >> 4)*18 + (m0 & 15);
    int pb1 = (m1 >> 4)*18 + (m1 & 15);
    const uint32_t kbase = (uint32_t)(hl*16);
    uint32_t baddr[9][2];
#pragma unroll
    for (int pos = 0; pos < 9; ++pos) {
        int d = (pos/3)*18 + (pos%3);
        int p0 = pb0 + d, p1 = pb1 + d;
        baddr[pos][0] = ((uint32_t)p0*64u + kbase) ^ (((uint32_t)(p0 & 7)) << 4);
        baddr[pos][1] = ((uint32_t)p1*64u + kbase) ^ (((uint32_t)(p1 & 7)) << 4);
    }
    const char* lds0 = (const char*)&lds[0][0];

    // A base: wave-uniform + lane; per-phase offsets are literals.
    // addr_e(ibk,pos,half,f) = cbnh*294912 + ibk*18432 + pos*2048
    //                        + half*1024 + f*512 + lane*8
    const __bf16* abase = Wt + (size_t)(cb*2 + nh)*294912u + (size_t)lane*8;

    // A prologue: slots 0,1 = (ibk0, ph0), (ibk0, ph1)
    bf16x8 A[3][2];
    A[0][0] = *(const bf16x8*)(abase + 0);
    A[0][1] = *(const bf16x8*)(abase + 512);
    A[1][0] = *(const bf16x8*)(abase + 1024);
    A[1][1] = *(const bf16x8*)(abase + 1536);

    __syncthreads();   // prologue: full drain once (DMA + joins waves)

// One ibk body. LAST is a literal: gates the DMA and the cross-ibk prefetch.
#define IBK_PHASES(LAST)                                                     \
    {                                                                        \
        bf16x8 Bb[2][2];                                                     \
        Bb[0][0] = *(const bf16x8*)(lds0 + baddr[0][0]);                     \
        Bb[0][1] = *(const bf16x8*)(lds0 + baddr[0][1]);                     \
        _Pragma("unroll")                                                    \
        for (int p = 0; p < 18; ++p) {                                       \
            /* A prefetch dist 2 into slot (p+2)%3; crosses ibk at p>=16 */  \
            {                                                                \
                const int tp = p + 2;                                        \
                const int xo = (tp < 18) ? 0 : ((LAST) ? -18432 : 0);        \
                const int off = ((tp < 18)                                   \
                    ? ((tp>>1)*2048 + (tp&1)*1024)                           \
                    : (18432 + (((tp-18)>>1)*2048 + ((tp-18)&1)*1024))) + xo;\
                A[(p+2)%3][0] = *(const bf16x8*)(abase + off);               \
                A[(p+2)%3][1] = *(const bf16x8*)(abase + off + 512);         \
            }                                                                \
            if (p == 1 && !(LAST)) {                                         \
                const unsigned char* np_ = planes + (size_t)(ibk+1)*PLANE_B; \
                _Pragma("unroll")                                            \
                for (int k = 0; k < 6; ++k)                                  \
                    gload_lds16(np_ + (size_t)(wv*6 + k)*1024u               \
                                    + (size_t)lane*16u,                      \
                                &lds[(ibk & 1) ^ 1][(wv*6 + k)*1024          \
                                                    + lane*16]);             \
            }                                                                \
            if (p < 17) {                                                    \
                const int np = p + 1;                                        \
                uint32_t a0 = baddr[np>>1][0] ^ (uint32_t)((np&1)*32);       \
                uint32_t a1 = baddr[np>>1][1] ^ (uint32_t)((np&1)*32);       \
                Bb[np&1][0] = *(const bf16x8*)(lds0 + a0);                   \
                Bb[np&1][1] = *(const bf16x8*)(lds0 + a1);                   \
            }                                                                \
            __builtin_amdgcn_s_setprio(1);                                   \
            acc[0][0] = __builtin_amdgcn_mfma_f32_32x32x16_bf16(A[p%3][0], Bb[p&1][0], acc[0][0], 0, 0, 0); \
            acc[0][1] = __builtin_amdgcn_mfma_f32_32x32x16_bf16(A[p%3][1], Bb[p&1][0], acc[0][1], 0, 0, 0); \
            acc[1][0] = __builtin_amdgcn_mfma_f32_32x32x16_bf16(A[p%3][0], Bb[p&1][1], acc[1][0], 0, 0, 0); \
            acc[1][1] = __builtin_amdgcn_mfma_f32_32x32x16_bf16(A[p%3][1], Bb[p&1][1], acc[1][1], 0, 0, 0); \
            __builtin_amdgcn_s_setprio(0);                                   \
        }                                                                    \
    }

    int flipd = 24576;   // +24576 / -24576 alternating buffer-flip (ADD, not XOR)
    for (int ibk = 0; ibk < 15; ++ibk) {
        IBK_PHASES(0)
        // flip B addresses to the other buffer; advance A base
#pragma unroll
        for (int pos = 0; pos < 9; ++pos) {
            baddr[pos][0] += (uint32_t)flipd;
            baddr[pos][1] += (uint32_t)flipd;
        }
        flipd = -flipd;
        abase += 18432;
        // Counted barrier (T4): 4 newest vmem ops (p16/p17 cross-ibk A
        // prefetches) stay in flight; DMA + older A loads must complete.
        asm volatile("s_waitcnt vmcnt(4) lgkmcnt(0)" ::: "memory");
        __builtin_amdgcn_s_barrier();
        __builtin_amdgcn_sched_barrier(0);
    }
    {
        const int ibk = 15;
        (void)ibk;
        IBK_PHASES(1)
    }
#undef IBK_PHASES

    // fused LSTM epilogue. col = l31 (m), r = 4*q + gate,
    // ch = cb*32 + fg*8 + 2*q + hl.
    float* outh = out;
    float* outc = out + (size_t)OUT_HALF;
    const size_t bOff = (size_t)b * (256*256);
#pragma unroll
    for (int mf = 0; mf < 2; ++mf) {
        int m = wv*64 + mf*32 + l31;
#pragma unroll
        for (int f = 0; f < 2; ++f) {
            int fg = nh*2 + f;
#pragma unroll
            for (int q = 0; q < 4; ++q) {
                int ch = cb*32 + fg*8 + 2*q + hl;
                size_t pidx = (size_t)ch*256 + (size_t)m;
                size_t idx  = bOff + pidx;
                float cv = cin[idx];
                float pi = acc[mf][f][4*q+0];
                float pf = acc[mf][f][4*q+1];
                float pc = acc[mf][f][4*q+2];
                float po = acc[mf][f][4*q+3];
                float it = 1.f/(1.f + __expf(-(pi + Wci[pidx]*cv)));
                float ft = 1.f/(1.f + __expf(-(pf + Wcf[pidx]*cv)));
                float tc = 1.f - 2.f/(1.f + __expf(2.f*pc));
                float ct = ft*cv + it*tc;
                float ot = 1.f/(1.f + __expf(-(po + Wco[pidx]*ct)));
                float th = 1.f - 2.f/(1.f + __expf(2.f*ct));
                outh[idx] = ot*th;
                outc[idx] = ct;
            }
        }
    }
}

// ---------------------------------------------------------------------------
extern "C" void kernel_launch(void* const* d_in, const int* in_sizes, int n_in,
                              void* d_out, int out_size, void* d_ws, size_t ws_size,
                              hipStream_t stream)
{
    const float* x   = (const float*)d_in[0];
    const float* h   = (const float*)d_in[1];
    const float* c   = (const float*)d_in[2];
    const float* Wx  = (const float*)d_in[3];
    const float* Wh  = (const float*)d_in[4];
    const float* bh  = (const float*)d_in[5];
    const float* Wci = (const float*)d_in[6];
    const float* Wcf = (const float*)d_in[7];
    const float* Wco = (const float*)d_in[8];
    float* out = (float*)d_out;

    unsigned char* xh = (unsigned char*)d_ws;        // padded plane store
    __bf16* Wt = (__bf16*)(xh + (size_t)XH_BYTES + 4096); // +slack

    hipLaunchKernelGGL(xh_transform, dim3(4096), dim3(256), 0, stream, x, h, xh);
    hipLaunchKernelGGL(w_transform,  dim3(2304), dim3(256), 0, stream, Wx, Wh, Wt);
    hipLaunchKernelGGL(convlstm_main, dim3(4096), dim3(256), 0, stream,
                       xh, Wt, bh, c, Wci, Wcf, Wco, out);
}